// Round 5
// baseline (935.075 us; speedup 1.0000x reference)
//
#include <hip/hip_runtime.h>
#include <hip/hip_bf16.h>
#include <stdint.h>

// DCLS2d: B=16, Cin=Cout=128, H=W=112, KH=KW=3, DIL=4, D=9, PAD=4
//
// Stage 1 (build_K): dense K (Cout,Cin,9,9) bf16, GEMM-ready slabs:
//   elem(tap,o,c) at ((tap*8+c/16)*2+(c/8)%2)*1024 + o*8 + (c%8); slab(tap,cc)
//   = 4 KB at byte offset (tap*8+cc)*4096.
// Stage 2 (dcls_conv): 81 tap-shifted GEMM accumulations, MFMA 32x32x16_bf16.
//   FAT-WAVE design: 128 threads = 2 waves/block, each wave owns ALL 4 Cout
//   tiles x 4 spatial n-tiles (16 MFMA/chunk-tap, acc = 256 regs -> AGPRs,
//   1 wave/SIMD). A-frags stream from global (L2) through a 3-slot register
//   ring prefetched 2 taps ahead (~1000 cyc cover); 81 % 3 == 0 makes slot
//   indices compile-time consistent across cc boundaries. B-frags from LDS
//   through a distance-1 ring (hides ~120cyc ds_read latency). No barriers
//   inside the tap loop; 2 barriers per cc for sX staging only.

typedef __attribute__((ext_vector_type(8))) short short8;
typedef __attribute__((ext_vector_type(16))) float f32x16;

__device__ inline unsigned short f2bf(float f) {
    union { float f; unsigned int u; } v; v.f = f;
    unsigned int u = v.u;
    return (unsigned short)((u + 0x7FFFu + ((u >> 16) & 1u)) >> 16); // RNE
}

__global__ void build_K(const float* __restrict__ weight,
                        const float* __restrict__ P,
                        unsigned short* __restrict__ Kws) {
    __shared__ float sacc[128 * 81];           // [c][tap], one o per block
    int tid = threadIdx.x;                     // 128 threads
    int o = blockIdx.x;
    int c = tid;
    float* a = &sacc[c * 81];
    for (int i = 0; i < 81; ++i) a[i] = 0.0f;
    int base = (o * 128 + c) * 9;
    #pragma unroll
    for (int kh = 0; kh < 3; ++kh) {
        #pragma unroll
        for (int kw = 0; kw < 3; ++kw) {
            int kk = kh * 3 + kw;
            float w  = weight[base + kk];
            float p0 = P[base + kk];
            float p1 = P[128 * 128 * 9 + base + kk];
            float ph = fminf(fmaxf((float)(kh * 4) + p0, 0.0f), 8.0f);
            float pw = fminf(fmaxf((float)(kw * 4) + p1, 0.0f), 8.0f);
            float fh = floorf(ph), fw = floorf(pw);
            float rh = ph - fh, rw = pw - fw;
            int ih = (int)fh, iw = (int)fw;
            int ih1 = min(ih + 1, 8), iw1 = min(iw + 1, 8);
            a[ih  * 9 + iw ] += w * (1.0f - rh) * (1.0f - rw);
            a[ih1 * 9 + iw ] += w * rh * (1.0f - rw);
            a[ih  * 9 + iw1] += w * (1.0f - rh) * rw;
            a[ih1 * 9 + iw1] += w * rh * rw;
        }
    }
    __syncthreads();
    // 1296 16B units per block (tap, chunk, half)
    for (int u = tid; u < 1296; u += 128) {
        int tap = u >> 4;
        int rem = u & 15;
        int chunk = rem >> 1, half = rem & 1;
        int c0 = chunk * 16 + half * 8;
        short8 v;
        #pragma unroll
        for (int j = 0; j < 8; ++j)
            v[j] = (short)f2bf(sacc[(c0 + j) * 81 + tap]);
        *(short8*)(Kws + ((tap * 8 + chunk) * 2 + half) * 1024 + o * 8) = v;
    }
}

// LDS: x window only: 24 rows x 2 c-halves x 24 cols x 16B = 18432 B
__global__ __launch_bounds__(128, 1)
void dcls_conv(const float* __restrict__ x,
               const unsigned short* __restrict__ Kws,
               const float* __restrict__ bias,
               float* __restrict__ out) {
    __shared__ __align__(16) char sX[18432];

    int bid = blockIdx.x;             // 784 = 16 * 7 * 7
    int b   = bid / 49;
    int rem = bid % 49;
    int ty  = rem / 7, tx = rem % 7;
    int y0  = ty * 16, x0 = tx * 16;

    int tid  = threadIdx.x;           // 128 = 2 waves
    int lane = tid & 63;
    int wave = tid >> 6;              // wave w owns n-tiles {4w..4w+3}, all 4 m
    int half = lane >> 5;             // c-half within 16-chunk
    int l31  = lane & 31;
    int lrow = (lane >> 4) & 1;       // row within n-tile
    int lcol = lane & 15;             // col within n-tile

    f32x16 acc[4][4];                 // [m][n] -> 256 regs (AGPR)
    #pragma unroll
    for (int i = 0; i < 4; ++i)
        #pragma unroll
        for (int j = 0; j < 4; ++j)
            #pragma unroll
            for (int k = 0; k < 16; ++k) acc[i][j][k] = 0.0f;

    int preA[4];                      // byte offsets within a 4KB slab
    #pragma unroll
    for (int i = 0; i < 4; ++i)
        preA[i] = half * 2048 + (i * 32 + l31) * 16;
    int preB[4];                      // byte offsets into sX
    #pragma unroll
    for (int j = 0; j < 4; ++j)
        preB[j] = (2 * (wave * 4 + j) + lrow) * 768 + half * 384 + lcol * 16;

    const char* __restrict__ Kb = (const char*)Kws;

    // A ring: 3 slots, prefetch distance 2. 81%3==0 -> slot=t%3 is globally
    // consistent across tap-groups and cc boundaries.
    short8 af[3][4];
    #pragma unroll
    for (int s = 0; s < 2; ++s) {     // preload taps 0,1 of cc=0 (slabs 0, 8)
        const char* kp = Kb + ((size_t)(s * 8) << 12);
        #pragma unroll
        for (int i = 0; i < 4; ++i)
            af[s][i] = *(const short8*)(kp + preA[i]);
    }
    short8 bfr[3][4];                 // B ring: 3 slots, distance 1

    for (int cc = 0; cc < 8; ++cc) {
        __syncthreads();              // previous cc's sX reads done
        // ---- stage x window (fp32 -> bf16), 1152 16B units, 9 per thread ----
        {
            int cbase = cc * 16;
            #pragma unroll
            for (int it = 0; it < 9; ++it) {
                int u = tid + it * 128;
                int r  = u / 48;
                int rr = u % 48;
                int hf = rr / 24;
                int co = rr % 24;
                int h = y0 - 4 + r;
                int w = x0 - 4 + co;
                bool ok = (h >= 0) & (h < 112) & (w >= 0) & (w < 112);
                const float* xp = x + (((b * 128 + cbase + hf * 8) * 112 + h) * 112 + w);
                short8 v;
                #pragma unroll
                for (int j = 0; j < 8; ++j) {
                    float f = ok ? xp[j * 112 * 112] : 0.0f;
                    v[j] = (short)f2bf(f);
                }
                *(short8*)(sX + u * 16) = v;
            }
        }
        __syncthreads();
        // preload B slot 0 (tap 0 of this cc)
        #pragma unroll
        for (int j = 0; j < 4; ++j)
            bfr[0][j] = *(const short8*)(sX + preB[j]);

        for (int tg = 0; tg < 9; ++tg) {
            #pragma unroll
            for (int t = 0; t < 9; ++t) {   // slot indices compile-time
                int tap = tg * 9 + t;
                const int cur  = t % 3;
                const int nxtB = (t + 1) % 3;
                const int nxtA = (t + 2) % 3;
                // A prefetch: tap+2 (rolls into next cc; clamp at the end)
                {
                    int aptap = tap + 2;
                    int pslab = (aptap <= 80) ? (aptap * 8 + cc)
                                              : ((aptap - 81) * 8 + cc + 1);
                    pslab = pslab < 647 ? pslab : 647;
                    const char* kp = Kb + ((size_t)pslab << 12);
                    #pragma unroll
                    for (int i = 0; i < 4; ++i)
                        af[nxtA][i] = *(const short8*)(kp + preA[i]);
                }
                // B prefetch: tap+1 within this cc (skip only at tg==8,t==8)
                if (t < 8 || tg < 8) {
                    int tapoff = (t == 8) ? ((tg + 1) * 768)
                                          : (tg * 768 + (t + 1) * 16);
                    #pragma unroll
                    for (int j = 0; j < 4; ++j)
                        bfr[nxtB][j] = *(const short8*)(sX + preB[j] + tapoff);
                }
                // 16 MFMAs on current slots
                #pragma unroll
                for (int i = 0; i < 4; ++i)
                    #pragma unroll
                    for (int j = 0; j < 4; ++j)
                        acc[i][j] = __builtin_amdgcn_mfma_f32_32x32x16_bf16(
                            af[cur][i], bfr[cur][j], acc[i][j], 0, 0, 0);
            }
        }
    }

    // ---- epilogue: C/D layout col=lane&31, row=(r&3)+8*(r>>2)+4*half ----
    #pragma unroll
    for (int i = 0; i < 4; ++i) {
        int ob = i * 32;
        #pragma unroll
        for (int r = 0; r < 16; ++r) {
            int o = ob + (r & 3) + 8 * (r >> 2) + 4 * half;
            float bv = bias[o];
            #pragma unroll
            for (int j = 0; j < 4; ++j) {
                int nt  = wave * 4 + j;
                int row = y0 + 2 * nt + lrow;
                int col = x0 + lcol;
                out[((b * 128 + o) * 112 + row) * 112 + col] = acc[i][j][r] + bv;
            }
        }
    }
}

extern "C" void kernel_launch(void* const* d_in, const int* in_sizes, int n_in,
                              void* d_out, int out_size, void* d_ws, size_t ws_size,
                              hipStream_t stream) {
    const float* x      = (const float*)d_in[0];
    const float* weight = (const float*)d_in[1];
    const float* P      = (const float*)d_in[2];
    const float* bias   = (const float*)d_in[3];
    float* out = (float*)d_out;
    unsigned short* Kws = (unsigned short*)d_ws;   // 81*128*128 bf16 = 2.65 MB

    build_K<<<128, 128, 0, stream>>>(weight, P, Kws);
    dcls_conv<<<784, 128, 0, stream>>>(x, Kws, bias, out);
}

// Round 6
// 612.316 us; speedup vs baseline: 1.5271x; 1.5271x over previous
//
#include <hip/hip_runtime.h>
#include <hip/hip_bf16.h>
#include <stdint.h>

// DCLS2d: B=16, Cin=Cout=128, H=W=112, KH=KW=3, DIL=4, D=9, PAD=4
//
// Stage 1 (build_K): dense K (Cout,Cin,9,9) bf16, GEMM-ready 4KB slabs:
//   elem(tap,o,c) at ((tap*8+c/16)*2+(c/8)%2)*1024 + o*8 + (c%8) [ushort].
// Stage 2 (dcls_conv): 81 tap-shifted GEMM accumulations, MFMA 32x32x16_bf16,
//   Cin reduced in chunks of 16 (cc loop). Both operands from LDS (compiler
//   schedules lgkmcnt well); K staged via global_load_lds DMA in groups of
//   3 taps, double-buffered, prefetch distance 2, with RAW
//   "s_waitcnt vmcnt(3); s_barrier" so prefetch DMAs stay in flight across
//   barriers (AITER-style; __syncthreads would drain vmcnt(0) and expose
//   L2 latency every group - the R1..R5 bottleneck).

typedef __attribute__((ext_vector_type(8))) short short8;
typedef __attribute__((ext_vector_type(16))) float f32x16;

__device__ inline unsigned short f2bf(float f) {
    union { float f; unsigned int u; } v; v.f = f;
    unsigned int u = v.u;
    return (unsigned short)((u + 0x7FFFu + ((u >> 16) & 1u)) >> 16); // RNE
}

__global__ void build_K(const float* __restrict__ weight,
                        const float* __restrict__ P,
                        unsigned short* __restrict__ Kws) {
    __shared__ float sacc[128 * 81];           // [c][tap], one o per block
    int tid = threadIdx.x;                     // 128 threads
    int o = blockIdx.x;
    int c = tid;
    float* a = &sacc[c * 81];
    for (int i = 0; i < 81; ++i) a[i] = 0.0f;
    int base = (o * 128 + c) * 9;
    #pragma unroll
    for (int kh = 0; kh < 3; ++kh) {
        #pragma unroll
        for (int kw = 0; kw < 3; ++kw) {
            int kk = kh * 3 + kw;
            float w  = weight[base + kk];
            float p0 = P[base + kk];
            float p1 = P[128 * 128 * 9 + base + kk];
            float ph = fminf(fmaxf((float)(kh * 4) + p0, 0.0f), 8.0f);
            float pw = fminf(fmaxf((float)(kw * 4) + p1, 0.0f), 8.0f);
            float fh = floorf(ph), fw = floorf(pw);
            float rh = ph - fh, rw = pw - fw;
            int ih = (int)fh, iw = (int)fw;
            int ih1 = min(ih + 1, 8), iw1 = min(iw + 1, 8);
            a[ih  * 9 + iw ] += w * (1.0f - rh) * (1.0f - rw);
            a[ih1 * 9 + iw ] += w * rh * (1.0f - rw);
            a[ih  * 9 + iw1] += w * (1.0f - rh) * rw;
            a[ih1 * 9 + iw1] += w * rh * rw;
        }
    }
    __syncthreads();
    // 1296 16B units per block (tap, chunk, half)
    for (int u = tid; u < 1296; u += 128) {
        int tap = u >> 4;
        int rem = u & 15;
        int chunk = rem >> 1, half = rem & 1;
        int c0 = chunk * 16 + half * 8;
        short8 v;
        #pragma unroll
        for (int j = 0; j < 8; ++j)
            v[j] = (short)f2bf(sacc[(c0 + j) * 81 + tap]);
        *(short8*)(Kws + ((tap * 8 + chunk) * 2 + half) * 1024 + o * 8) = v;
    }
}

__device__ inline void dma3(const char* Kb, char* dst, int tapbase, int cc,
                            int woff, int lane16) {
    // 3 slabs of 4KB; wave covers its 1KB quarter of each slab.
    // dst is wave-uniform; HW scatters lane i at dst + i*16.
    #pragma unroll
    for (int j = 0; j < 3; ++j) {
        const char* src = Kb + (((size_t)((tapbase + j) * 8 + cc)) << 12)
                             + woff + lane16;
        __builtin_amdgcn_global_load_lds(
            (const __attribute__((address_space(1))) char*)src,
            (__attribute__((address_space(3))) char*)(dst + j * 4096 + woff),
            16, 0, 0);
    }
}

// LDS: sX 18432 (x window, per cc) + 2 x 12288 (sK dbuf, 3 taps each) = 43008
__global__ __launch_bounds__(256, 2)
void dcls_conv(const float* __restrict__ x,
               const unsigned short* __restrict__ Kws,
               const float* __restrict__ bias,
               float* __restrict__ out) {
    __shared__ __align__(16) char sX[18432];
    __shared__ __align__(16) char sK0[12288];
    __shared__ __align__(16) char sK1[12288];

    int bid = blockIdx.x;             // 784 = 16 * 7 * 7
    int b   = bid / 49;
    int rem = bid % 49;
    int ty  = rem / 7, tx = rem % 7;
    int y0  = ty * 16, x0 = tx * 16;

    int tid  = threadIdx.x;
    int lane = tid & 63;
    int wave = tid >> 6;
    int mgrp = wave >> 1;             // m-tiles {2m, 2m+1}
    int ngrp = wave & 1;              // n-tiles {4n..4n+3}
    int half = lane >> 5;             // c-half within 16-chunk
    int l31  = lane & 31;
    int lrow = (lane >> 4) & 1;
    int lcol = lane & 15;
    int woff = wave * 1024;           // DMA wave quarter
    int lane16 = lane * 16;

    f32x16 acc[2][4];
    #pragma unroll
    for (int i = 0; i < 2; ++i)
        #pragma unroll
        for (int j = 0; j < 4; ++j)
            #pragma unroll
            for (int k = 0; k < 16; ++k) acc[i][j][k] = 0.0f;

    int preA[2];                      // byte offsets within a 4KB slab
    #pragma unroll
    for (int i = 0; i < 2; ++i)
        preA[i] = half * 2048 + ((mgrp * 2 + i) * 32 + l31) * 16;
    int preB[4];                      // byte offsets into sX
    #pragma unroll
    for (int j = 0; j < 4; ++j)
        preB[j] = (2 * (ngrp * 4 + j) + lrow) * 768 + half * 384 + lcol * 16;

    const char* __restrict__ Kb = (const char*)Kws;

    for (int cc = 0; cc < 8; ++cc) {
        __syncthreads();              // prev cc's reads done; drains all counters
        // ---- stage x window (fp32 -> bf16), 1152 16B units ----
        {
            int cbase = cc * 16;
            #pragma unroll
            for (int it = 0; it < 5; ++it) {
                int u = tid + it * 256;
                if (u < 1152) {
                    int r  = u / 48;
                    int rr = u % 48;
                    int hf = rr / 24;
                    int co = rr % 24;
                    int h = y0 - 4 + r;
                    int w = x0 - 4 + co;
                    bool ok = (h >= 0) & (h < 112) & (w >= 0) & (w < 112);
                    const float* xp = x + (((b * 128 + cbase + hf * 8) * 112 + h) * 112 + w);
                    short8 v;
                    #pragma unroll
                    for (int j = 0; j < 8; ++j) {
                        float f = ok ? xp[j * 112 * 112] : 0.0f;
                        v[j] = (short)f2bf(f);
                    }
                    *(short8*)(sX + u * 16) = v;
                }
            }
        }
        __syncthreads();              // sX visible; vmcnt drained (0 outstanding)

        // ---- pipelined K-DMA + compute: 27 groups of 3 taps ----
        dma3(Kb, sK0, 0, cc, woff, lane16);   // G0
        dma3(Kb, sK1, 3, cc, woff, lane16);   // G1

        int tg = 0, t = 0;
        for (int g = 0; g < 27; ++g) {
            // wait for group g's DMAs (keep group g+1's 3 in flight)
            if (g < 26) {
                asm volatile("s_waitcnt vmcnt(3)\n\ts_barrier" ::: "memory");
            } else {
                asm volatile("s_waitcnt vmcnt(0)\n\ts_barrier" ::: "memory");
            }
            char* buf = (g & 1) ? sK1 : sK0;
            #pragma unroll
            for (int j = 0; j < 3; ++j) {
                int tapoff = tg * 768 + t * 16;
                short8 af[2];
                #pragma unroll
                for (int i = 0; i < 2; ++i)
                    af[i] = *(const short8*)(buf + j * 4096 + preA[i]);
                short8 bfr[4];
                #pragma unroll
                for (int jj = 0; jj < 4; ++jj)
                    bfr[jj] = *(const short8*)(sX + preB[jj] + tapoff);
                #pragma unroll
                for (int i = 0; i < 2; ++i)
                    #pragma unroll
                    for (int jj = 0; jj < 4; ++jj)
                        acc[i][jj] = __builtin_amdgcn_mfma_f32_32x32x16_bf16(
                            af[i], bfr[jj], acc[i][jj], 0, 0, 0);
                if (++t == 9) { t = 0; ++tg; }
            }
            if (g < 25) {
                // all waves done reading buf before DMA overwrites it
                asm volatile("s_barrier" ::: "memory");
                dma3(Kb, buf, (g + 2) * 3, cc, woff, lane16);  // G(g+2)
            }
        }
    }

    // ---- epilogue: C/D layout col=lane&31, row=(r&3)+8*(r>>2)+4*half ----
    #pragma unroll
    for (int i = 0; i < 2; ++i) {
        int ob = (mgrp * 2 + i) * 32;
        #pragma unroll
        for (int r = 0; r < 16; ++r) {
            int o = ob + (r & 3) + 8 * (r >> 2) + 4 * half;
            float bv = bias[o];
            #pragma unroll
            for (int j = 0; j < 4; ++j) {
                int nt  = ngrp * 4 + j;
                int row = y0 + 2 * nt + lrow;
                int col = x0 + lcol;
                out[((b * 128 + o) * 112 + row) * 112 + col] = acc[i][j][r] + bv;
            }
        }
    }
}

extern "C" void kernel_launch(void* const* d_in, const int* in_sizes, int n_in,
                              void* d_out, int out_size, void* d_ws, size_t ws_size,
                              hipStream_t stream) {
    const float* x      = (const float*)d_in[0];
    const float* weight = (const float*)d_in[1];
    const float* P      = (const float*)d_in[2];
    const float* bias   = (const float*)d_in[3];
    float* out = (float*)d_out;
    unsigned short* Kws = (unsigned short*)d_ws;   // 81*128*128 bf16 = 2.65 MB

    build_K<<<128, 128, 0, stream>>>(weight, P, Kws);
    dcls_conv<<<784, 256, 0, stream>>>(x, Kws, bias, out);
}